// Round 1
// baseline (142.172 us; speedup 1.0000x reference)
//
#include <hip/hip_runtime.h>
#include <hip/hip_bf16.h>

// Problem constants
#define B_    32
#define M_    1024
#define H_    128
#define SPAN_ 1024
#define KL_   2048
#define NITER 17     // (1024 + 64) / 64 key tiles per 64-row q block

typedef __attribute__((ext_vector_type(8))) short bf16x8;
typedef __attribute__((ext_vector_type(4))) float f32x4;

// LDS layout (bytes)
#define PITCH_A  264   // [64][132] bf16 : Q / pos-chunk (PT) / K tiles
#define PITCH_VT 152   // [128][76] bf16 : V transposed
#define PITCH_PR 256   // [64][128] bf16 : bias ring (2 chunks of 64 l-cols)
#define PITCH_PW 136   // [64][68]  bf16 : probabilities
#define OFF_PT 0
#define OFF_K  16896
#define OFF_VT 33792
#define OFF_PR 53248
#define OFF_PW 69632
#define LDS_TOTAL 78336

static __device__ __forceinline__ unsigned short f2b(float x) {
  // round-to-nearest-even f32 -> bf16
  unsigned int u = __builtin_bit_cast(unsigned int, x);
  unsigned int r = (u + 0x7FFFu + ((u >> 16) & 1u)) >> 16;
  return (unsigned short)r;
}
static __device__ __forceinline__ float b2f(unsigned short u) {
  return __builtin_bit_cast(float, ((unsigned int)u) << 16);
}

static __device__ __forceinline__ bf16x8 ldfrag(const char* p) {
  short4 a = *(const short4*)p;
  short4 b = *(const short4*)(p + 8);
  bf16x8 r;
  r[0] = a.x; r[1] = a.y; r[2] = a.z; r[3] = a.w;
  r[4] = b.x; r[5] = b.y; r[6] = b.z; r[7] = b.w;
  return r;
}

__global__ void __launch_bounds__(256, 2) seqattn_kernel(
    const float* __restrict__ q, const float* __restrict__ kkey,
    const float* __restrict__ vval, const float* __restrict__ pe,
    float* __restrict__ out) {
  extern __shared__ char smem[];
  char* PT = smem + OFF_PT;   // pos chunk (also Q staging at start)
  char* KL = smem + OFF_K;    // K tile
  char* VT = smem + OFF_VT;   // V tile transposed
  char* PR = smem + OFF_PR;   // bias ring
  char* PW = smem + OFF_PW;   // probabilities

  // XCD-aware swizzle: consecutive logical blocks (same b, adjacent m0) on one XCD
  int j = blockIdx.x;
  int o = (j & 7) * 64 + (j >> 3);
  int b  = o >> 4;
  int m0 = (o & 15) * 64;

  int tid  = threadIdx.x;
  int w    = tid >> 6;
  int lane = tid & 63;
  int g    = lane >> 4;
  int c    = lane & 15;

  const float* qbase = q    + ((size_t)b * M_  + m0) * H_;
  const float* kbase = kkey + ((size_t)b * KL_ + m0) * H_;
  const float* vbase = vval + ((size_t)b * KL_ + m0) * H_;

  // ---- stage Q (64x128 f32 -> bf16) into PT region ----
  {
    int r0 = tid >> 5, c4 = tid & 31;
#pragma unroll
    for (int p = 0; p < 8; ++p) {
      int row = p * 8 + r0;
      float4 v = *(const float4*)(qbase + row * H_ + c4 * 4);
      ushort4 h4;
      h4.x = f2b(v.x); h4.y = f2b(v.y); h4.z = f2b(v.z); h4.w = f2b(v.w);
      *(ushort4*)(PT + row * PITCH_A + c4 * 8) = h4;
    }
  }
  __syncthreads();

  // ---- Q fragments (kept in registers; wave w owns rows [16w,16w+16)) ----
  bf16x8 qf[4];
#pragma unroll
  for (int hs = 0; hs < 4; ++hs)
    qf[hs] = ldfrag(PT + (w * 16 + c) * PITCH_A + hs * 64 + g * 16);

  f32x4 O[8];
#pragma unroll
  for (int i = 0; i < 8; ++i) { O[i][0] = 0.f; O[i][1] = 0.f; O[i][2] = 0.f; O[i][3] = 0.f; }
  float mrun[4], lrun[4];
#pragma unroll
  for (int r = 0; r < 4; ++r) { mrun[r] = -1e30f; lrun[r] = 0.f; }

  for (int t = 0; t < NITER; ++t) {
    __syncthreads();  // protect LDS tiles (and initial Q frags) before restage

    // ---- stage K tile (rows m0+64t .. +63) ----
    {
      const float* kb = kbase + (size_t)(64 * t) * H_;
      int r0 = tid >> 5, c4 = tid & 31;
#pragma unroll
      for (int p = 0; p < 8; ++p) {
        int row = p * 8 + r0;
        float4 v = *(const float4*)(kb + row * H_ + c4 * 4);
        ushort4 h4;
        h4.x = f2b(v.x); h4.y = f2b(v.y); h4.z = f2b(v.z); h4.w = f2b(v.w);
        *(ushort4*)(KL + row * PITCH_A + c4 * 8) = h4;
      }
    }
    // ---- stage V tile transposed: VT[h][kk] ----
    {
      const float* vb = vbase + (size_t)(64 * t) * H_;
#pragma unroll
      for (int qq = 0; qq < 4; ++qq) {
        int kq = w * 4 + qq;  // 4 consecutive k-rows
        float2 x0 = *(const float2*)(vb + (4 * kq + 0) * H_ + 2 * lane);
        float2 x1 = *(const float2*)(vb + (4 * kq + 1) * H_ + 2 * lane);
        float2 x2 = *(const float2*)(vb + (4 * kq + 2) * H_ + 2 * lane);
        float2 x3 = *(const float2*)(vb + (4 * kq + 3) * H_ + 2 * lane);
        ushort4 lo; lo.x = f2b(x0.x); lo.y = f2b(x1.x); lo.z = f2b(x2.x); lo.w = f2b(x3.x);
        ushort4 hi; hi.x = f2b(x0.y); hi.y = f2b(x1.y); hi.z = f2b(x2.y); hi.w = f2b(x3.y);
        *(ushort4*)(VT + (2 * lane + 0) * PITCH_VT + 8 * kq) = lo;
        *(ushort4*)(VT + (2 * lane + 1) * PITCH_VT + 8 * kq) = hi;
      }
    }
    // ---- stage pos chunk transposed: PT[lcol][h], lcol in [64t, 64t+64) ----
    if (t < 16) {
      const float* pb = pe + 64 * t;
#pragma unroll
      for (int qq = 0; qq < 8; ++qq) {
        int hq = w * 8 + qq;
        float a0 = pb[(4 * hq + 0) * SPAN_ + lane];
        float a1 = pb[(4 * hq + 1) * SPAN_ + lane];
        float a2 = pb[(4 * hq + 2) * SPAN_ + lane];
        float a3 = pb[(4 * hq + 3) * SPAN_ + lane];
        ushort4 h4; h4.x = f2b(a0); h4.y = f2b(a1); h4.z = f2b(a2); h4.w = f2b(a3);
        *(ushort4*)(PT + lane * PITCH_A + 8 * hq) = h4;
      }
    }
    __syncthreads();

    // ---- bias chunk via MFMA: ring[row][l&127] = q[row] . pos[:, l] ----
    if (t < 16) {
#pragma unroll
      for (int lt = 0; lt < 4; ++lt) {
        f32x4 pb = {0.f, 0.f, 0.f, 0.f};
#pragma unroll
        for (int hs = 0; hs < 4; ++hs)
          pb = __builtin_amdgcn_mfma_f32_16x16x32_bf16(
              qf[hs], ldfrag(PT + (16 * lt + c) * PITCH_A + hs * 64 + g * 16), pb, 0, 0, 0);
        int lcol = 64 * t + 16 * lt + c;
#pragma unroll
        for (int rr = 0; rr < 4; ++rr) {
          int row = w * 16 + 4 * g + rr;
          *(unsigned short*)(PR + row * PITCH_PR + (lcol & 127) * 2) = f2b(pb[rr]);
        }
      }
    }

    // ---- S = Q K^T ----
    f32x4 s[4];
#pragma unroll
    for (int nt = 0; nt < 4; ++nt) {
      f32x4 acc = {0.f, 0.f, 0.f, 0.f};
#pragma unroll
      for (int hs = 0; hs < 4; ++hs)
        acc = __builtin_amdgcn_mfma_f32_16x16x32_bf16(
            qf[hs], ldfrag(KL + (16 * nt + c) * PITCH_A + hs * 64 + g * 16), acc, 0, 0, 0);
      s[nt] = acc;
    }

    // ---- epilogue: add bias (ring lookup), mask band, online softmax ----
    float tmax[4] = {-1e30f, -1e30f, -1e30f, -1e30f};
#pragma unroll
    for (int nt = 0; nt < 4; ++nt)
#pragma unroll
      for (int rr = 0; rr < 4; ++rr) {
        int iloc = w * 16 + 4 * g + rr;
        int l = 64 * t + 16 * nt + c - iloc;
        float sv;
        if ((unsigned)l < 1024u) {
          float bias = b2f(*(const unsigned short*)(PR + iloc * PITCH_PR + (l & 127) * 2));
          sv = (s[nt][rr] + bias) * 0.08838834764831845f;
        } else {
          sv = -1e30f;
        }
        s[nt][rr] = sv;
        tmax[rr] = fmaxf(tmax[rr], sv);
      }
#pragma unroll
    for (int rr = 0; rr < 4; ++rr) {
      float t0 = tmax[rr];
      t0 = fmaxf(t0, __shfl_xor(t0, 1, 16));
      t0 = fmaxf(t0, __shfl_xor(t0, 2, 16));
      t0 = fmaxf(t0, __shfl_xor(t0, 4, 16));
      t0 = fmaxf(t0, __shfl_xor(t0, 8, 16));
      tmax[rr] = t0;
    }
    float corr[4], rsum[4];
#pragma unroll
    for (int rr = 0; rr < 4; ++rr) {
      float mn = fmaxf(mrun[rr], tmax[rr]);
      corr[rr] = __expf(mrun[rr] - mn);
      mrun[rr] = mn;
      rsum[rr] = 0.f;
    }
#pragma unroll
    for (int nt = 0; nt < 4; ++nt)
#pragma unroll
      for (int rr = 0; rr < 4; ++rr) {
        float p = __expf(s[nt][rr] - mrun[rr]);
        s[nt][rr] = p;
        rsum[rr] += p;
      }
#pragma unroll
    for (int rr = 0; rr < 4; ++rr) {
      float r0 = rsum[rr];
      r0 += __shfl_xor(r0, 1, 16);
      r0 += __shfl_xor(r0, 2, 16);
      r0 += __shfl_xor(r0, 4, 16);
      r0 += __shfl_xor(r0, 8, 16);
      lrun[rr] = lrun[rr] * corr[rr] + r0;
    }
#pragma unroll
    for (int nt = 0; nt < 8; ++nt) {
      O[nt][0] *= corr[0]; O[nt][1] *= corr[1];
      O[nt][2] *= corr[2]; O[nt][3] *= corr[3];
    }
    // ---- probabilities -> LDS (wave-private rows) ----
#pragma unroll
    for (int nt = 0; nt < 4; ++nt)
#pragma unroll
      for (int rr = 0; rr < 4; ++rr)
        *(unsigned short*)(PW + (w * 16 + 4 * g + rr) * PITCH_PW + (16 * nt + c) * 2) =
            f2b(s[nt][rr]);
    // ---- O += P V ----
#pragma unroll
    for (int ks = 0; ks < 2; ++ks) {
      bf16x8 pa = ldfrag(PW + (w * 16 + c) * PITCH_PW + ks * 64 + g * 16);
#pragma unroll
      for (int nt = 0; nt < 8; ++nt)
        O[nt] = __builtin_amdgcn_mfma_f32_16x16x32_bf16(
            pa, ldfrag(VT + (16 * nt + c) * PITCH_VT + ks * 64 + g * 16), O[nt], 0, 0, 0);
    }
  }

  // ---- final normalize + store ----
  float inv[4];
#pragma unroll
  for (int rr = 0; rr < 4; ++rr) inv[rr] = 1.0f / lrun[rr];
  float* ob = out + ((size_t)b * M_ + m0 + w * 16) * H_;
#pragma unroll
  for (int nt = 0; nt < 8; ++nt)
#pragma unroll
    for (int rr = 0; rr < 4; ++rr)
      ob[(4 * g + rr) * H_ + 16 * nt + c] = O[nt][rr] * inv[rr];
}

extern "C" void kernel_launch(void* const* d_in, const int* in_sizes, int n_in,
                              void* d_out, int out_size, void* d_ws, size_t ws_size,
                              hipStream_t stream) {
  const float* q  = (const float*)d_in[0];
  const float* k  = (const float*)d_in[1];
  const float* v  = (const float*)d_in[2];
  const float* pe = (const float*)d_in[3];
  float* out = (float*)d_out;

  hipFuncSetAttribute(reinterpret_cast<const void*>(seqattn_kernel),
                      hipFuncAttributeMaxDynamicSharedMemorySize, LDS_TOTAL);
  seqattn_kernel<<<dim3(512), dim3(256), LDS_TOTAL, stream>>>(q, k, v, pe, out);
}

// Round 2
// 79.066 us; speedup vs baseline: 1.7981x; 1.7981x over previous
//
#include <hip/hip_runtime.h>
#include <hip/hip_bf16.h>

// Problem constants
#define B_    32
#define M_    1024
#define H_    128
#define SPAN_ 1024
#define KL_   2048
#define NITER 17     // (1024 + 64) / 64 key tiles per 64-row q block

typedef __attribute__((ext_vector_type(8))) short bf16x8;
typedef __attribute__((ext_vector_type(4))) float f32x4;

// LDS layout (bytes)
#define PITCH_A  264   // [64][132] bf16 : K tile / pos chunk (l-major)
#define PITCH_VT 136   // [128][68] bf16 : V transposed
#define PITCH_PR 264   // [64][128+pad] bf16 : bias ring, x=(l+m)&127  (also Q staging)
#define PITCH_PW 136   // [64][68]  bf16 : probabilities (row-major, m rows)
#define OFF_K  0
#define OFF_VT 16896
#define OFF_PT 34304
#define OFF_PR 51200
#define OFF_PW 68096
#define LDS_TOTAL 76800
#define SCALE 0.08838834764831845f

static __device__ __forceinline__ unsigned int cvt_pk2(float lo, float hi) {
  unsigned int r;
  asm("v_cvt_pk_bf16_f32 %0, %1, %2" : "=v"(r) : "v"(lo), "v"(hi));
  return r;
}
static __device__ __forceinline__ unsigned short f2b(float x) {
  unsigned int u = __builtin_bit_cast(unsigned int, x);
  return (unsigned short)((u + 0x7FFFu + ((u >> 16) & 1u)) >> 16);
}
static __device__ __forceinline__ float b2f(unsigned short u) {
  return __builtin_bit_cast(float, ((unsigned int)u) << 16);
}
static __device__ __forceinline__ bf16x8 ldfrag(const char* p) {
  short4 a = *(const short4*)p;
  short4 b = *(const short4*)(p + 8);
  bf16x8 r;
  r[0] = a.x; r[1] = a.y; r[2] = a.z; r[3] = a.w;
  r[4] = b.x; r[5] = b.y; r[6] = b.z; r[7] = b.w;
  return r;
}

__global__ void __launch_bounds__(256, 2) seqattn_kernel(
    const float* __restrict__ q, const float* __restrict__ kkey,
    const float* __restrict__ vval, const float* __restrict__ pe,
    float* __restrict__ out) {
  extern __shared__ char smem[];
  char* KL = smem + OFF_K;    // K tile (j rows)
  char* VT = smem + OFF_VT;   // V^T tile (h rows, k cols)
  char* PT = smem + OFF_PT;   // pos chunk (l rows, h cols)
  char* PR = smem + OFF_PR;   // bias ring (m rows, x=(l+m)&127)  + Q staging at start
  char* PW = smem + OFF_PW;   // probabilities (m rows, j cols)

  // XCD-aware swizzle
  int jb = blockIdx.x;
  int o  = (jb & 7) * 64 + (jb >> 3);
  int b  = o >> 4;
  int m0 = (o & 15) * 64;

  int tid  = threadIdx.x;
  int w    = tid >> 6;
  int lane = tid & 63;
  int g    = lane >> 4;
  int c    = lane & 15;
  int r0   = tid >> 5;   // staging row sub-index (0..7)
  int c4   = tid & 31;   // staging col sub-index (0..31)

  const float* qbase = q    + ((size_t)b * M_  + m0) * H_;
  const float* kbase = kkey + ((size_t)b * KL_ + m0) * H_;
  const float* vbase = vval + ((size_t)b * KL_ + m0) * H_;

  float4 kpre[8];
  float  vpre[32];   // [qq][r][half]
  float  ppre[32];   // [qq][r]

#define LOADK(tt) do {                                                        \
    const float* kb_ = kbase + (size_t)(64 * (tt)) * H_;                      \
    _Pragma("unroll")                                                         \
    for (int p = 0; p < 8; ++p)                                               \
      kpre[p] = *(const float4*)(kb_ + (p * 8 + r0) * H_ + c4 * 4);           \
  } while (0)

#define WRITEK() do {                                                         \
    _Pragma("unroll")                                                         \
    for (int p = 0; p < 8; ++p) {                                             \
      float4 v_ = kpre[p];                                                    \
      uint2 d_; d_.x = cvt_pk2(v_.x, v_.y); d_.y = cvt_pk2(v_.z, v_.w);       \
      *(uint2*)(KL + (p * 8 + r0) * PITCH_A + c4 * 8) = d_;                   \
    }                                                                         \
  } while (0)

#define LOADV(tt) do {                                                        \
    const float* vb_ = vbase + (size_t)(64 * (tt)) * H_;                      \
    _Pragma("unroll")                                                         \
    for (int qq = 0; qq < 4; ++qq) {                                          \
      int kq_ = 4 * (4 * w + qq);                                             \
      _Pragma("unroll")                                                       \
      for (int r = 0; r < 4; ++r) {                                           \
        vpre[qq * 8 + r * 2 + 0] = vb_[(kq_ + r) * H_ + lane];                \
        vpre[qq * 8 + r * 2 + 1] = vb_[(kq_ + r) * H_ + lane + 64];           \
      }                                                                       \
    }                                                                         \
  } while (0)

#define WRITEV() do {                                                         \
    _Pragma("unroll")                                                         \
    for (int qq = 0; qq < 4; ++qq) {                                          \
      int kq_ = 4 * w + qq;                                                   \
      uint2 lo_, hi_;                                                         \
      lo_.x = cvt_pk2(vpre[qq * 8 + 0], vpre[qq * 8 + 2]);                    \
      lo_.y = cvt_pk2(vpre[qq * 8 + 4], vpre[qq * 8 + 6]);                    \
      hi_.x = cvt_pk2(vpre[qq * 8 + 1], vpre[qq * 8 + 3]);                    \
      hi_.y = cvt_pk2(vpre[qq * 8 + 5], vpre[qq * 8 + 7]);                    \
      *(uint2*)(VT + lane * PITCH_VT + 8 * kq_) = lo_;                        \
      *(uint2*)(VT + (lane + 64) * PITCH_VT + 8 * kq_) = hi_;                 \
    }                                                                         \
  } while (0)

#define LOADP(tt) do {                                                        \
    const float* pb_ = pe + 64 * (tt);                                        \
    _Pragma("unroll")                                                         \
    for (int qq = 0; qq < 8; ++qq) {                                          \
      int h_ = 4 * (8 * w + qq);                                              \
      _Pragma("unroll")                                                       \
      for (int r = 0; r < 4; ++r)                                             \
        ppre[qq * 4 + r] = pb_[(h_ + r) * SPAN_ + lane];                      \
    }                                                                         \
  } while (0)

#define WRITEP() do {                                                         \
    _Pragma("unroll")                                                         \
    for (int qq = 0; qq < 8; ++qq) {                                          \
      uint2 d_;                                                               \
      d_.x = cvt_pk2(ppre[qq * 4 + 0], ppre[qq * 4 + 1]);                     \
      d_.y = cvt_pk2(ppre[qq * 4 + 2], ppre[qq * 4 + 3]);                     \
      *(uint2*)(PT + lane * PITCH_A + 8 * (8 * w + qq)) = d_;                 \
    }                                                                         \
  } while (0)

  // ---- prologue: Q + tile 0, then issue tile 1 ----
  {
    float4 qpre[8];
#pragma unroll
    for (int p = 0; p < 8; ++p)
      qpre[p] = *(const float4*)(qbase + (p * 8 + r0) * H_ + c4 * 4);
    LOADK(0); LOADV(0); LOADP(0);
#pragma unroll
    for (int p = 0; p < 8; ++p) {
      float4 v_ = qpre[p];
      uint2 d_;
      d_.x = cvt_pk2(v_.x * SCALE, v_.y * SCALE);
      d_.y = cvt_pk2(v_.z * SCALE, v_.w * SCALE);
      *(uint2*)(PR + (p * 8 + r0) * PITCH_PR + c4 * 8) = d_;
    }
    WRITEK(); WRITEV(); WRITEP();
    LOADK(1); LOADV(1); LOADP(1);
  }
  __syncthreads();

  // Q fragments (pre-scaled by 1/sqrt(H)); wave w owns rows [16w,16w+16)
  bf16x8 qf[4];
#pragma unroll
  for (int hs = 0; hs < 4; ++hs)
    qf[hs] = ldfrag(PR + (w * 16 + c) * PITCH_PR + hs * 64 + g * 16);

  f32x4 O[8];
#pragma unroll
  for (int i = 0; i < 8; ++i) { O[i][0] = 0.f; O[i][1] = 0.f; O[i][2] = 0.f; O[i][3] = 0.f; }
  float mrun = -1e30f, lrun = 0.f;
  const int mrow = 16 * w + c;              // this lane's q-row (block-local)
  char* prRow = PR + mrow * PITCH_PR;
  char* pwRow = PW + mrow * PITCH_PW;

#pragma unroll 1
  for (int t = 0; t < NITER; ++t) {
    // ---- bias chunk (transposed MFMA): lane holds bias[mrow][l=64t+16lt+4g+rr] ----
    if (t < 16) {
#pragma unroll
      for (int lt = 0; lt < 4; ++lt) {
        f32x4 pb = {0.f, 0.f, 0.f, 0.f};
#pragma unroll
        for (int hs = 0; hs < 4; ++hs)
          pb = __builtin_amdgcn_mfma_f32_16x16x32_bf16(
              ldfrag(PT + (16 * lt + c) * PITCH_A + hs * 64 + g * 16), qf[hs], pb, 0, 0, 0);
#pragma unroll
        for (int rr = 0; rr < 4; ++rr) {
          int x = (64 * t + 16 * lt + 4 * g + rr + mrow) & 127;
          *(unsigned short*)(prRow + x * 2) = f2b(pb[rr]);
        }
      }
    }

    // ---- S^T = K Q^T : lane (g,c) elem rr = S[mrow][j=64t+16nt+4g+rr] ----
    f32x4 s[4];
#pragma unroll
    for (int nt = 0; nt < 4; ++nt) {
      f32x4 acc = {0.f, 0.f, 0.f, 0.f};
#pragma unroll
      for (int hs = 0; hs < 4; ++hs)
        acc = __builtin_amdgcn_mfma_f32_16x16x32_bf16(
            ldfrag(KL + (16 * nt + c) * PITCH_A + hs * 64 + g * 16), qf[hs], acc, 0, 0, 0);
      s[nt] = acc;
    }

    // ---- bias add (aligned b64 ring reads) + band mask ----
#pragma unroll
    for (int nt = 0; nt < 4; ++nt) {
      int x = (64 * t + 16 * nt + 4 * g) & 127;          // multiple of 4 -> 8B aligned
      ushort4 bv = *(const ushort4*)(prRow + x * 2);
      int lbase = 64 * t + 16 * nt + 4 * g - mrow;
      const unsigned short* bp = (const unsigned short*)&bv;
#pragma unroll
      for (int rr = 0; rr < 4; ++rr) {
        float sv = s[nt][rr] + b2f(bp[rr]);
        s[nt][rr] = ((unsigned)(lbase + rr) < 1024u) ? sv : -1e30f;
      }
    }

    // ---- online softmax (per-lane row) with defer-max ----
    float pmax = -1e30f;
#pragma unroll
    for (int nt = 0; nt < 4; ++nt)
#pragma unroll
      for (int rr = 0; rr < 4; ++rr) pmax = fmaxf(pmax, s[nt][rr]);
    pmax = fmaxf(pmax, __shfl_xor(pmax, 16, 64));
    pmax = fmaxf(pmax, __shfl_xor(pmax, 32, 64));

    if (__any(pmax > mrun + 8.0f)) {
      float mn = fmaxf(mrun, pmax);
      float corr = __expf(mrun - mn);
      mrun = mn;
      lrun *= corr;
#pragma unroll
      for (int i = 0; i < 8; ++i) {
        O[i][0] *= corr; O[i][1] *= corr; O[i][2] *= corr; O[i][3] *= corr;
      }
    }

    float rsum = 0.f;
#pragma unroll
    for (int nt = 0; nt < 4; ++nt) {
      float p0 = __expf(s[nt][0] - mrun);
      float p1 = __expf(s[nt][1] - mrun);
      float p2 = __expf(s[nt][2] - mrun);
      float p3 = __expf(s[nt][3] - mrun);
      rsum += (p0 + p1) + (p2 + p3);
      uint2 d_;
      d_.x = cvt_pk2(p0, p1);
      d_.y = cvt_pk2(p2, p3);
      *(uint2*)(pwRow + (16 * nt + 4 * g) * 2) = d_;    // P[mrow][j] (8B aligned)
    }
    rsum += __shfl_xor(rsum, 16, 64);
    rsum += __shfl_xor(rsum, 32, 64);
    lrun += rsum;

    // ---- O^T += V^T P^T : lane (g,c) elem rr = O[mrow][h=16nt+4g+rr] ----
#pragma unroll
    for (int ks = 0; ks < 2; ++ks) {
      bf16x8 pfrag = ldfrag(pwRow + ks * 64 + g * 16);
#pragma unroll
      for (int nt = 0; nt < 8; ++nt)
        O[nt] = __builtin_amdgcn_mfma_f32_16x16x32_bf16(
            ldfrag(VT + (16 * nt + c) * PITCH_VT + ks * 64 + g * 16), pfrag, O[nt], 0, 0, 0);
    }

    __syncthreads();   // all waves done reading KL/VT/PT tile t
    if (t < 16) {
      WRITEK(); WRITEV();             // stage tile t+1 (regs loaded an iter ago)
      if (t < 15) {
        WRITEP();                     // pos tile t+1 (exists iff t+1 < 16)
        LOADK(t + 2); LOADV(t + 2);   // issue prefetch for tile t+2
        if (t + 2 < 16) LOADP(t + 2);
      }
    }
    __syncthreads();
  }

  // ---- normalize + store (float4 per nt) ----
  float inv = 1.0f / lrun;
  float* ob = out + ((size_t)b * M_ + m0 + mrow) * H_;
#pragma unroll
  for (int nt = 0; nt < 8; ++nt) {
    float4 vv;
    vv.x = O[nt][0] * inv; vv.y = O[nt][1] * inv;
    vv.z = O[nt][2] * inv; vv.w = O[nt][3] * inv;
    *(float4*)(ob + 16 * nt + 4 * g) = vv;
  }
}

extern "C" void kernel_launch(void* const* d_in, const int* in_sizes, int n_in,
                              void* d_out, int out_size, void* d_ws, size_t ws_size,
                              hipStream_t stream) {
  const float* q  = (const float*)d_in[0];
  const float* k  = (const float*)d_in[1];
  const float* v  = (const float*)d_in[2];
  const float* pe = (const float*)d_in[3];
  float* out = (float*)d_out;

  hipFuncSetAttribute(reinterpret_cast<const void*>(seqattn_kernel),
                      hipFuncAttributeMaxDynamicSharedMemorySize, LDS_TOTAL);
  seqattn_kernel<<<dim3(512), dim3(256), LDS_TOTAL, stream>>>(q, k, v, pe, out);
}